// Round 1
// baseline (1268.840 us; speedup 1.0000x reference)
//
#include <hip/hip_runtime.h>

// Householder flow step, fused:
//   v_new = v @ W^T + b ; z_new = z - 2 v_new (v_new.z)/||v_new||^2
// B = 524288 rows, d = 128, all fp32.
//
// Layout: lane l owns output columns j = 2l, 2l+1 of its wave's rows.
// W staged transposed in LDS (Wt[k][j], stride 130 -> 8B aligned ds_read_b64,
// 2-way bank aliasing = free). v row values are wave-uniform -> scalar loads.

#define ZD 128
#define LSTR 130          // 128 + 2 pad: even (b64 align) and breaks stride-128 conflicts
#define BLOCK 512         // 8 waves
#define ROWS_PER_BLOCK 128

template<int R>
__device__ __forceinline__ void process_rows(
    const float* __restrict__ z, const float* __restrict__ v,
    float* __restrict__ out, const float* Wt,
    int row0, int lane, float b0, float b1)
{
    float2 zr[R];
    float acc0[R], acc1[R];
    const float* vp = v + (size_t)row0 * ZD;   // wave-uniform pointer
    #pragma unroll
    for (int r = 0; r < R; ++r) {
        zr[r] = *(const float2*)(z + (size_t)(row0 + r) * ZD + 2 * lane);
        acc0[r] = 0.f; acc1[r] = 0.f;
    }
    #pragma unroll
    for (int k = 0; k < ZD; ++k) {
        float2 wv = *(const float2*)(Wt + k * LSTR + 2 * lane);  // ds_read_b64
        #pragma unroll
        for (int r = 0; r < R; ++r) {
            float vk = vp[r * ZD + k];         // uniform -> s_load
            acc0[r] = fmaf(vk, wv.x, acc0[r]);
            acc1[r] = fmaf(vk, wv.y, acc1[r]);
        }
    }
    #pragma unroll
    for (int r = 0; r < R; ++r) {
        float a0 = acc0[r] + b0;
        float a1 = acc1[r] + b1;
        float dot = a0 * zr[r].x + a1 * zr[r].y;
        float nrm = a0 * a0 + a1 * a1;
        #pragma unroll
        for (int off = 32; off; off >>= 1) {
            dot += __shfl_xor(dot, off);
            nrm += __shfl_xor(nrm, off);
        }
        float s = 2.0f * dot / nrm;
        float2 o;
        o.x = zr[r].x - s * a0;
        o.y = zr[r].y - s * a1;
        *(float2*)(out + (size_t)(row0 + r) * ZD + 2 * lane) = o;
    }
}

__global__ __launch_bounds__(BLOCK)
void hh_kernel(const float* __restrict__ z, const float* __restrict__ v,
               const float* __restrict__ W, const float* __restrict__ bias,
               float* __restrict__ out, int rows)
{
    __shared__ float Wt[ZD * LSTR];
    const int tid = threadIdx.x;
    // Stage W transposed: Wt[k*LSTR + j] = W[j*128 + k].
    // Global read coalesced; LDS write stride 130 dwords -> 2-way alias (free).
    #pragma unroll
    for (int i = tid; i < ZD * ZD; i += BLOCK) {
        int j = i >> 7, k = i & 127;
        Wt[k * LSTR + j] = W[i];
    }
    __syncthreads();

    const int lane = tid & 63;
    const int wid  = __builtin_amdgcn_readfirstlane(tid >> 6);  // force uniform
    float2 bb = *(const float2*)(bias + 2 * lane);

    const int rowBase = blockIdx.x * ROWS_PER_BLOCK + wid * 16;
    #pragma unroll 1
    for (int t = 0; t < 4; ++t) {
        int row0 = rowBase + t * 4;
        if (row0 >= rows) return;
        if (row0 + 4 <= rows) {
            process_rows<4>(z, v, out, Wt, row0, lane, bb.x, bb.y);
        } else {
            for (int r = 0; r < 4 && row0 + r < rows; ++r)
                process_rows<1>(z, v, out, Wt, row0 + r, lane, bb.x, bb.y);
        }
    }
}

extern "C" void kernel_launch(void* const* d_in, const int* in_sizes, int n_in,
                              void* d_out, int out_size, void* d_ws, size_t ws_size,
                              hipStream_t stream) {
    const float* z    = (const float*)d_in[0];
    const float* v    = (const float*)d_in[1];
    const float* W    = (const float*)d_in[2];
    const float* bias = (const float*)d_in[3];
    float* out = (float*)d_out;
    int rows = in_sizes[0] / ZD;
    int grid = (rows + ROWS_PER_BLOCK - 1) / ROWS_PER_BLOCK;
    hh_kernel<<<grid, BLOCK, 0, stream>>>(z, v, W, bias, out, rows);
}